// Round 4
// baseline (385.271 us; speedup 1.0000x reference)
//
#include <hip/hip_runtime.h>
#include <hip/hip_fp16.h>

typedef _Float16 f16;
typedef __attribute__((ext_vector_type(8))) _Float16 f16x8;
typedef __attribute__((ext_vector_type(4))) _Float16 f16x4;
typedef __attribute__((ext_vector_type(4))) float f32x4;

#define BM 256
#define BN 256
#define BK 32

__device__ __forceinline__ void gll16(const void* src, void* dst) {
  __builtin_amdgcn_global_load_lds((const __attribute__((address_space(1))) void*)src,
                                   (__attribute__((address_space(3))) void*)dst,
                                   16, 0, 0);
}

// C[m,n] = sum_k A[m,k] * B[n,k]  ("BT" form; both operands row-major along K)
// 256x256 tile, BK=32, 512 thr (8 waves 2Mx4N). 3-buffer LDS ring (96 KiB), linear
// layout (64B rows => <=2-way bank aliasing on ds_read_b128, free per m136).
// Counted vmcnt (T3+T4): during tile kt stage tile kt+2 (A in ph0, B in ph1) into
// buf (kt+2)%3 — safe: that buf's ds_reads all returned at tile kt-1's last
// lgkmcnt(0), before the boundary barrier every wave passed. Boundary waits
// vmcnt(4): tile kt+1 (issued a full tile ago) landed; kt+2's 4 loads STAY IN
// FLIGHT => memory pipe never empties (m218's counted-vmcnt lever).
// T1 XCD swizzle: contiguous logical chunks per XCD (all grids %8==0).
// MODE 0: store C fp16
// MODE 1: p = exp(acc*scale + mask[row,col]); store fp16 P; row-sum partials -> lvec (32/row)
// MODE 2: store C fp32 = acc * (1 / lvec[z*M + row])
template<int MODE>
__global__ __launch_bounds__(512, 2)
void gemm_bt(const f16* __restrict__ Aall, const f16* __restrict__ Ball,
             void* __restrict__ Call,
             int M, int N, int K, int lda, int ldb, int ldc,
             long strideA, long strideB, long strideC,
             const float* __restrict__ maskAll, long strideMask,
             float* __restrict__ lvec, float scale)
{
  __shared__ __align__(16) f16 smA[3][BM * BK];   // 3 x 16 KB
  __shared__ __align__(16) f16 smB[3][BN * BK];   // 3 x 16 KB  -> 96 KiB

  // ---- T1: bijective XCD-aware block remap (nwg % 8 == 0 for all our grids)
  unsigned gx = gridDim.x, gy = gridDim.y;
  unsigned id = (blockIdx.z * gy + blockIdx.y) * gx + blockIdx.x;
  unsigned nwg = gx * gy * gridDim.z;
  unsigned swz = (id & 7) * (nwg >> 3) + (id >> 3);
  unsigned bx = swz % gx, rem = swz / gx;
  unsigned by = rem % gy, bz = rem / gy;

  const int z = bz;
  const f16* A = Aall + (long)z * strideA;
  const f16* B = Ball + (long)z * strideB;

  const int tid  = threadIdx.x;
  const int wid  = tid >> 6;
  const int lane = tid & 63;
  const int wm = wid >> 2;        // 0..1 -> 128 rows of C
  const int wn = wid & 3;         // 0..3 -> 64 cols of C
  const int lr = lane & 15;
  const int g  = lane >> 4;       // k-slot 0..3 (8 f16 each)

  const long brow = (long)by * BM;
  const long bcol = (long)bx * BN;
  const int  nt   = K / BK;

  f32x4 acc[8][4] = {};

  // Stage a 256x32 f16 tile (16 KB = 1024 x 16B chunks; 2 chunks/thread), linear.
  // chunk c: row = c>>2 (4 chunks/row = 64B = full row), dest = base + c*16B.
  auto stA = [&](int buf, int t) {
    #pragma unroll
    for (int i = 0; i < 2; ++i) {
      int c   = i * 512 + tid;
      int row = c >> 2;
      gll16(A + (brow + row) * (long)lda + t * BK + (c & 3) * 8, &smA[buf][c * 8]);
    }
  };
  auto stB = [&](int buf, int t) {
    #pragma unroll
    for (int i = 0; i < 2; ++i) {
      int c   = i * 512 + tid;
      int row = c >> 2;
      gll16(B + (bcol + row) * (long)ldb + t * BK + (c & 3) * 8, &smB[buf][c * 8]);
    }
  };
  auto ld = [&](const f16* base, int r) -> f16x8 {
    return *(const f16x8*)(base + r * BK + g * 8);
  };

  // prologue: tiles 0,1 staged; wait tile 0 (tile 1's 4 loads stay in flight)
  stA(0, 0); stB(0, 0);
  stA(1, 1); stB(1, 1);
  asm volatile("s_waitcnt vmcnt(4)" ::: "memory");
  __builtin_amdgcn_s_barrier();

  int b0 = 0, bn = 2;
  for (int kt = 0; kt < nt; ++kt) {
    const f16* sa = smA[b0];
    const f16* sb = smB[b0];
    const bool pf = (kt + 2 < nt);
    f16x8 af[4], bf[4];

    // ---- ph0: bf + af(m0-3); stage A(kt+2); MFMA q0
    #pragma unroll
    for (int n = 0; n < 4; ++n) bf[n] = ld(sb, wn * 64 + n * 16 + lr);
    #pragma unroll
    for (int m = 0; m < 4; ++m) af[m] = ld(sa, wm * 128 + m * 16 + lr);
    if (pf) stA(bn, kt + 2);
    __builtin_amdgcn_s_barrier();
    asm volatile("s_waitcnt lgkmcnt(0)" ::: "memory");
    __builtin_amdgcn_sched_barrier(0);
    __builtin_amdgcn_s_setprio(1);
    #pragma unroll
    for (int m = 0; m < 4; ++m)
      #pragma unroll
      for (int n = 0; n < 4; ++n)
        acc[m][n] = __builtin_amdgcn_mfma_f32_16x16x32_f16(af[m], bf[n], acc[m][n], 0, 0, 0);
    __builtin_amdgcn_s_setprio(0);
    __builtin_amdgcn_s_barrier();

    // ---- ph1: af(m4-7); stage B(kt+2); MFMA q1; boundary vmcnt(4)
    #pragma unroll
    for (int m = 0; m < 4; ++m) af[m] = ld(sa, wm * 128 + 64 + m * 16 + lr);
    if (pf) stB(bn, kt + 2);
    __builtin_amdgcn_s_barrier();
    asm volatile("s_waitcnt lgkmcnt(0)" ::: "memory");
    __builtin_amdgcn_sched_barrier(0);
    __builtin_amdgcn_s_setprio(1);
    #pragma unroll
    for (int m = 0; m < 4; ++m)
      #pragma unroll
      for (int n = 0; n < 4; ++n)
        acc[m + 4][n] = __builtin_amdgcn_mfma_f32_16x16x32_f16(af[m], bf[n], acc[m + 4][n], 0, 0, 0);
    __builtin_amdgcn_s_setprio(0);
    __builtin_amdgcn_sched_barrier(0);
    if (pf) { asm volatile("s_waitcnt vmcnt(4)" ::: "memory"); }   // kt+1 landed; kt+2 in flight
    else    { asm volatile("s_waitcnt vmcnt(0)" ::: "memory"); }   // tail tiles
    __builtin_amdgcn_s_barrier();
    b0 = b0 + 1 == 3 ? 0 : b0 + 1;
    bn = bn + 1 == 3 ? 0 : bn + 1;
  }

  // C/D layout (m89-verified): col = lane&15, row = (lane>>4)*4 + reg
  const int rb = (lane >> 4) * 4;

  if (MODE == 0) {
    f16* C = (f16*)Call + (long)z * strideC;
    #pragma unroll
    for (int m = 0; m < 8; ++m)
      #pragma unroll
      for (int j = 0; j < 4; ++j) {
        long grow = brow + wm * 128 + m * 16 + rb + j;
        #pragma unroll
        for (int n = 0; n < 4; ++n) {
          long gcol = bcol + wn * 64 + n * 16 + lr;
          C[grow * ldc + gcol] = (f16)acc[m][n][j];
        }
      }
  } else if (MODE == 1) {
    f16* C = (f16*)Call + (long)z * strideC;
    const float* mask = maskAll + (long)z * strideMask;
    #pragma unroll
    for (int m = 0; m < 8; ++m)
      #pragma unroll
      for (int j = 0; j < 4; ++j) {
        long grow = brow + wm * 128 + m * 16 + rb + j;
        float s = 0.f;
        #pragma unroll
        for (int n = 0; n < 4; ++n) {
          long gcol = bcol + wn * 64 + n * 16 + lr;
          float p = __expf(acc[m][n][j] * scale + mask[grow * ldc + gcol]);
          C[grow * ldc + gcol] = (f16)p;
          s += p;
        }
        s += __shfl_xor(s, 1);
        s += __shfl_xor(s, 2);
        s += __shfl_xor(s, 4);
        s += __shfl_xor(s, 8);
        if (lr == 0)
          lvec[((long)z * M + grow) * 32 + bx * 4 + wn] = s;
      }
  } else {
    float* C = (float*)Call + (long)z * strideC;
    #pragma unroll
    for (int m = 0; m < 8; ++m)
      #pragma unroll
      for (int j = 0; j < 4; ++j) {
        long grow = brow + wm * 128 + m * 16 + rb + j;
        float inv = 1.0f / lvec[(long)z * M + grow];
        #pragma unroll
        for (int n = 0; n < 4; ++n) {
          long gcol = bcol + wn * 64 + n * 16 + lr;
          C[grow * ldc + gcol] = acc[m][n][j] * inv;
        }
      }
  }
}

// one grid-strided kernel converting q,k,v,Wq,Wk,Wv fp32 -> fp16
__global__ void cvt_all(const float* __restrict__ q, const float* __restrict__ k,
                        const float* __restrict__ v, const float* __restrict__ Wq,
                        const float* __restrict__ Wk, const float* __restrict__ Wv,
                        f16* __restrict__ qf, f16* __restrict__ kf, f16* __restrict__ vf,
                        f16* __restrict__ Wqf, f16* __restrict__ Wkf, f16* __restrict__ Wvf)
{
  const long NQ4 = 4194304, NW4 = 262144;       // float4 counts
  const long total = 3 * NQ4 + 3 * NW4;
  for (long i = (long)blockIdx.x * blockDim.x + threadIdx.x; i < total;
       i += (long)gridDim.x * blockDim.x) {
    const float* src; f16* dst; long j = i;
    if      (j <     NQ4)           { src = q;  dst = qf; }
    else if (j < 2 * NQ4)           { src = k;  dst = kf;  j -= NQ4; }
    else if (j < 3 * NQ4)           { src = v;  dst = vf;  j -= 2 * NQ4; }
    else if (j < 3 * NQ4 + NW4)     { src = Wq; dst = Wqf; j -= 3 * NQ4; }
    else if (j < 3 * NQ4 + 2 * NW4) { src = Wk; dst = Wkf; j -= 3 * NQ4 + NW4; }
    else                            { src = Wv; dst = Wvf; j -= 3 * NQ4 + 2 * NW4; }
    float4 vv = ((const float4*)src)[j];
    f16x4 o;
    o[0] = (f16)vv.x; o[1] = (f16)vv.y; o[2] = (f16)vv.z; o[3] = (f16)vv.w;
    ((f16x4*)dst)[j] = o;
  }
}

__global__ void reduce_l(const float* __restrict__ lpart, float* __restrict__ lsum, int n) {
  int i = blockIdx.x * blockDim.x + threadIdx.x;
  if (i < n) {
    float s = 0.f;
    #pragma unroll
    for (int j = 0; j < 32; ++j) s += lpart[(long)i * 32 + j];
    lsum[i] = s;
  }
}

extern "C" void kernel_launch(void* const* d_in, const int* in_sizes, int n_in,
                              void* d_out, int out_size, void* d_ws, size_t ws_size,
                              hipStream_t stream)
{
  const float* q    = (const float*)d_in[0];
  const float* k    = (const float*)d_in[1];
  const float* v    = (const float*)d_in[2];
  const float* mask = (const float*)d_in[3];
  const float* Wq   = (const float*)d_in[4];
  const float* Wk   = (const float*)d_in[5];
  const float* Wv   = (const float*)d_in[6];
  float* out = (float*)d_out;
  char*  ws  = (char*)d_ws;

  // workspace layout (bytes); q/k/v fp16 region is dead after projections -> reused for P
  f16* qf  = (f16*)(ws + 0);            // 32 MB
  f16* kf  = (f16*)(ws + 33554432);     // 32 MB
  f16* vf  = (f16*)(ws + 67108864);     // 32 MB
  f16* Pm  = (f16*)(ws + 0);            // 64 MB (reuse of qf/kf/vf region)
  f16* Wqf = (f16*)(ws + 100663296);    // 2 MB
  f16* Wkf = (f16*)(ws + 102760448);
  f16* Wvf = (f16*)(ws + 104857600);
  f16* qp  = (f16*)(ws + 106954752);    // 32 MB
  f16* kp  = (f16*)(ws + 140509184);    // 32 MB
  f16* vpT = (f16*)(ws + 174063616);    // 32 MB  (stored H x J, i.e. transposed)
  float* lpart = (float*)(ws + 207618048); // 2 MB
  float* lsum  = (float*)(ws + 209715200); // 64 KB

  const long L = 2048, J = 2048, D = 1024, H = 1024;

  // 1) fp32 -> fp16 converts (single launch)
  cvt_all<<<dim3(2048), dim3(256), 0, stream>>>(q, k, v, Wq, Wk, Wv, qf, kf, vf, Wqf, Wkf, Wvf);

  // 2) projections
  // qp[bl,h] = sum_d q[bl,d] * Wq[h,d]     M=16384 N=1024 K=1024
  gemm_bt<0><<<dim3(1024 / BN, 16384 / BM, 1), dim3(512), 0, stream>>>(
      qf, Wqf, qp, 16384, 1024, 1024, 1024, 1024, 1024,
      0, 0, 0, nullptr, 0, nullptr, 0.f);
  // kp[bj,h] = sum_d k[bj,d] * Wk[h,d]
  gemm_bt<0><<<dim3(1024 / BN, 16384 / BM, 1), dim3(512), 0, stream>>>(
      kf, Wkf, kp, 16384, 1024, 1024, 1024, 1024, 1024,
      0, 0, 0, nullptr, 0, nullptr, 0.f);
  // vpT[b][h,j] = sum_d Wv[h,d] * v[b][j,d]   M=1024 N=2048 K=1024, batched over b
  gemm_bt<0><<<dim3(2048 / BN, 1024 / BM, 8), dim3(512), 0, stream>>>(
      Wvf, vf, vpT, 1024, 2048, 1024, 1024, 1024, 2048,
      0, J * D, H * J, nullptr, 0, nullptr, 0.f);

  // 3) P[b][l,j] = exp(qp.kp^T / 32 + mask), fp16, + row-sum partials
  gemm_bt<1><<<dim3(2048 / BN, 2048 / BM, 8), dim3(512), 0, stream>>>(
      qp, kp, Pm, 2048, 2048, 1024, 1024, 1024, 2048,
      L * H, J * H, L * J, mask, L * J, lpart, 0.03125f);

  reduce_l<<<dim3(16384 / 256), dim3(256), 0, stream>>>(lpart, lsum, 16384);

  // 4) out[b][l,h] = (sum_j P[l,j] * vpT[h,j]) / l[b,l]   M=2048 N=1024 K=2048
  gemm_bt<2><<<dim3(1024 / BN, 2048 / BM, 8), dim3(512), 0, stream>>>(
      Pm, vpT, out, 2048, 1024, 2048, 2048, 2048, 1024,
      L * J, H * J, L * H, nullptr, 0, lsum, 0.f);
}

// Round 5
// 377.048 us; speedup vs baseline: 1.0218x; 1.0218x over previous
//
#include <hip/hip_runtime.h>
#include <hip/hip_fp16.h>

typedef _Float16 f16;
typedef __attribute__((ext_vector_type(8))) _Float16 f16x8;
typedef __attribute__((ext_vector_type(4))) _Float16 f16x4;
typedef __attribute__((ext_vector_type(4))) float f32x4;

#define BM 256
#define BN 256
#define BK 64

__device__ __forceinline__ void gll16(const void* src, void* dst) {
  __builtin_amdgcn_global_load_lds((const __attribute__((address_space(1))) void*)src,
                                   (__attribute__((address_space(3))) void*)dst,
                                   16, 0, 0);
}

// C[m,n] = sum_k A[m,k] * B[n,k]  ("BT" form).
// m201 8-phase schedule, derived + hazard-checked:
//  - 256x256 tile, BK=64, 512 thr (8 waves 2Mx4N), 128 KiB LDS.
//  - even K-tiles in smX[0], odd in smX[1]. Iter i = tiles (2i, 2i+1), 8 phases.
//  - per phase: {ds_reads || stage ONE half-tile (2 gll/thr) -> barrier ->
//    lgkmcnt(0)+sched_barrier -> setprio(1) 16 MFMA setprio(0) -> barrier}.
//  - stage slots (t=2i): ph1:A-hi(t+1) ph2:A-lo(t+1) ph3:B-hi(t+2) ph4:B-lo(t+2)
//    ph5:A-hi(t+2) ph6:A-lo(t+2) ph7:B-hi(t+3) ph8:B-lo(t+3).
//    Each staged region's readers finished >=1 barrier earlier (checked per half).
//  - waits: vmcnt(4) ONLY at ph4 & ph8 (FIFO: lands the stage issued 2 phases
//    earlier; every half-tile is staged >=4 phases before first consumption;
//    in-flight never drains to 0). Last iter: ph4 uses vmcnt(0), ph8 none.
//  - swizzle: linear slot s of row r holds global slot s^(r&7) (BK=64 row=128B
//    drops out of bank index; measured 0 conflicts in R1/R3).
// MODE 0: C fp16   MODE 1: P=exp(acc*scale+mask), fp16 + row-sum partials
// MODE 2: C fp32 = acc / lvec[row]
template<int MODE>
__global__ __launch_bounds__(512, 2)
void gemm_bt(const f16* __restrict__ Aall, const f16* __restrict__ Ball,
             void* __restrict__ Call,
             int M, int N, int K, int lda, int ldb, int ldc,
             long strideA, long strideB, long strideC,
             const float* __restrict__ maskAll, long strideMask,
             float* __restrict__ lvec, float scale)
{
  __shared__ __align__(16) f16 smA[2][BM * BK];   // 2 x 32 KB
  __shared__ __align__(16) f16 smB[2][BN * BK];   // 2 x 32 KB  -> 128 KiB

  // T1: bijective XCD-aware remap (all grids have nwg % 8 == 0)
  unsigned gx = gridDim.x, gy = gridDim.y;
  unsigned id = (blockIdx.z * gy + blockIdx.y) * gx + blockIdx.x;
  unsigned nwg = gx * gy * gridDim.z;
  unsigned swz = (id & 7) * (nwg >> 3) + (id >> 3);
  unsigned bx = swz % gx, rem = swz / gx;
  unsigned by = rem % gy, bz = rem / gy;

  const int z = bz;
  const f16* A = Aall + (long)z * strideA;
  const f16* B = Ball + (long)z * strideB;

  const int tid  = threadIdx.x;
  const int wid  = tid >> 6;
  const int lane = tid & 63;
  const int wm = wid >> 2;        // 0..1 -> 128 rows of C
  const int wn = wid & 3;         // 0..3 -> 64 cols of C
  const int lr = lane & 15;
  const int g  = lane >> 4;       // k-slot 0..3 (8 f16 each)

  const long brow = (long)by * BM;
  const long bcol = (long)bx * BN;
  const int  nt   = K / BK;       // >= 4, even

  f32x4 acc[8][4] = {};
  f16x8 af[8], bf[8];

  // stage one 128-row half-tile (16 KB, 2 gll/thread). LDS dest linear
  // (wave-uniform base + lane*16); source pre-swizzled by slot^(row&7).
  auto stage_half = [&](f16* dst, const f16* src, long prow, int ld_, int rowOff, int t) {
    #pragma unroll
    for (int i = 0; i < 2; ++i) {
      int c  = i * 512 + tid;
      int r  = c >> 3;
      int sl = (c & 7) ^ (r & 7);
      gll16(src + (prow + rowOff + r) * (long)ld_ + t * BK + sl * 8,
            dst + rowOff * BK + c * 8);
    }
  };
  auto rdA = [&](const f16* sa, int mh) {        // af[fm*2+ks] for wave rows wm*128+mh*64+..
    #pragma unroll
    for (int fm = 0; fm < 4; ++fm)
      #pragma unroll
      for (int ks = 0; ks < 2; ++ks) {
        int r = wm * 128 + mh * 64 + fm * 16 + lr;
        af[fm * 2 + ks] = *(const f16x8*)(sa + r * BK + ((ks * 4 + g) ^ (r & 7)) * 8);
      }
  };
  auto rdB = [&](const f16* sb, int nh) {        // bf[(nh*2+fn)*2+ks]
    #pragma unroll
    for (int fn = 0; fn < 2; ++fn)
      #pragma unroll
      for (int ks = 0; ks < 2; ++ks) {
        int r = wn * 64 + (nh * 2 + fn) * 16 + lr;
        bf[(nh * 2 + fn) * 2 + ks] = *(const f16x8*)(sb + r * BK + ((ks * 4 + g) ^ (r & 7)) * 8);
      }
  };
  auto sync_mfma = [&](int fm0, int fn0) {       // called with literal fm0/fn0 (static idx)
    __builtin_amdgcn_s_barrier();
    asm volatile("s_waitcnt lgkmcnt(0)" ::: "memory");
    __builtin_amdgcn_sched_barrier(0);
    __builtin_amdgcn_s_setprio(1);
    #pragma unroll
    for (int fm = 0; fm < 4; ++fm)
      #pragma unroll
      for (int fn = 0; fn < 2; ++fn)
        #pragma unroll
        for (int ks = 0; ks < 2; ++ks)
          acc[fm0 + fm][fn0 + fn] = __builtin_amdgcn_mfma_f32_16x16x32_f16(
              af[fm * 2 + ks], bf[(fn0 + fn) * 2 + ks], acc[fm0 + fm][fn0 + fn], 0, 0, 0);
    __builtin_amdgcn_s_setprio(0);
    __builtin_amdgcn_s_barrier();
  };

  // prologue: tile0 (both arrays) + tile1 B-halves; A(1) comes in iter0 ph1/ph2.
  stage_half(smA[0], A, brow, lda, 0, 0);
  stage_half(smA[0], A, brow, lda, 128, 0);
  stage_half(smB[0], B, bcol, ldb, 0, 0);
  stage_half(smB[0], B, bcol, ldb, 128, 0);
  stage_half(smB[1], B, bcol, ldb, 0, 1);
  stage_half(smB[1], B, bcol, ldb, 128, 1);
  asm volatile("s_waitcnt vmcnt(4)" ::: "memory");   // tile0's 8 landed; B(1) in flight
  __builtin_amdgcn_s_barrier();

  const int niter = nt / 2;
  for (int i = 0; i < niter; ++i) {
    const bool last = (i == niter - 1);
    const int t2 = 2 * i + 2, t3 = 2 * i + 3;

    // ph1: reads buf0 A-hi + B n0-1 ; stage A-hi(2i+1)
    rdA(smA[0], 0); rdB(smB[0], 0);
    stage_half(smA[1], A, brow, lda, 0, 2 * i + 1);
    sync_mfma(0, 0);
    // ph2: reads buf0 B n2-3 ; stage A-lo(2i+1)
    rdB(smB[0], 1);
    stage_half(smA[1], A, brow, lda, 128, 2 * i + 1);
    sync_mfma(0, 2);
    // ph3: reads buf0 A-lo(m4-7) ; stage B-hi(t2)
    rdA(smA[0], 1);
    if (t2 < nt) stage_half(smB[0], B, bcol, ldb, 0, t2);
    sync_mfma(4, 2);
    // ph4: no reads ; stage B-lo(t2) ; counted wait
    if (t2 < nt) stage_half(smB[0], B, bcol, ldb, 128, t2);
    if (!last) { asm volatile("s_waitcnt vmcnt(4)" ::: "memory"); }
    else       { asm volatile("s_waitcnt vmcnt(0)" ::: "memory"); }
    sync_mfma(4, 0);
    // ph5: reads buf1 A-hi + B n0-1 ; stage A-hi(t2)
    rdA(smA[1], 0); rdB(smB[1], 0);
    if (t2 < nt) stage_half(smA[0], A, brow, lda, 0, t2);
    sync_mfma(0, 0);
    // ph6: reads buf1 B n2-3 ; stage A-lo(t2)
    rdB(smB[1], 1);
    if (t2 < nt) stage_half(smA[0], A, brow, lda, 128, t2);
    sync_mfma(0, 2);
    // ph7: reads buf1 A-lo ; stage B-hi(t3)
    rdA(smA[1], 1);
    if (t3 < nt) stage_half(smB[1], B, bcol, ldb, 0, t3);
    sync_mfma(4, 2);
    // ph8: stage B-lo(t3) ; counted wait
    if (t3 < nt) stage_half(smB[1], B, bcol, ldb, 128, t3);
    if (!last) { asm volatile("s_waitcnt vmcnt(4)" ::: "memory"); }
    sync_mfma(4, 0);
  }

  // C/D layout (m89-verified): col = lane&15, row = (lane>>4)*4 + reg
  const int rb = (lane >> 4) * 4;

  if (MODE == 0) {
    f16* C = (f16*)Call + (long)z * strideC;
    #pragma unroll
    for (int m = 0; m < 8; ++m)
      #pragma unroll
      for (int j = 0; j < 4; ++j) {
        long grow = brow + wm * 128 + m * 16 + rb + j;
        #pragma unroll
        for (int n = 0; n < 4; ++n) {
          long gcol = bcol + wn * 64 + n * 16 + lr;
          C[grow * ldc + gcol] = (f16)acc[m][n][j];
        }
      }
  } else if (MODE == 1) {
    f16* C = (f16*)Call + (long)z * strideC;
    const float* mask = maskAll + (long)z * strideMask;
    #pragma unroll
    for (int m = 0; m < 8; ++m)
      #pragma unroll
      for (int j = 0; j < 4; ++j) {
        long grow = brow + wm * 128 + m * 16 + rb + j;
        float s = 0.f;
        #pragma unroll
        for (int n = 0; n < 4; ++n) {
          long gcol = bcol + wn * 64 + n * 16 + lr;
          float p = __expf(acc[m][n][j] * scale + mask[grow * ldc + gcol]);
          C[grow * ldc + gcol] = (f16)p;
          s += p;
        }
        s += __shfl_xor(s, 1);
        s += __shfl_xor(s, 2);
        s += __shfl_xor(s, 4);
        s += __shfl_xor(s, 8);
        if (lr == 0)
          lvec[((long)z * M + grow) * 32 + bx * 4 + wn] = s;
      }
  } else {
    float* C = (float*)Call + (long)z * strideC;
    #pragma unroll
    for (int m = 0; m < 8; ++m)
      #pragma unroll
      for (int j = 0; j < 4; ++j) {
        long grow = brow + wm * 128 + m * 16 + rb + j;
        float inv = 1.0f / lvec[(long)z * M + grow];
        #pragma unroll
        for (int n = 0; n < 4; ++n) {
          long gcol = bcol + wn * 64 + n * 16 + lr;
          C[grow * ldc + gcol] = acc[m][n][j] * inv;
        }
      }
  }
}

// one grid-strided kernel converting q,k,v,Wq,Wk,Wv fp32 -> fp16
__global__ void cvt_all(const float* __restrict__ q, const float* __restrict__ k,
                        const float* __restrict__ v, const float* __restrict__ Wq,
                        const float* __restrict__ Wk, const float* __restrict__ Wv,
                        f16* __restrict__ qf, f16* __restrict__ kf, f16* __restrict__ vf,
                        f16* __restrict__ Wqf, f16* __restrict__ Wkf, f16* __restrict__ Wvf)
{
  const long NQ4 = 4194304, NW4 = 262144;       // float4 counts
  const long total = 3 * NQ4 + 3 * NW4;
  for (long i = (long)blockIdx.x * blockDim.x + threadIdx.x; i < total;
       i += (long)gridDim.x * blockDim.x) {
    const float* src; f16* dst; long j = i;
    if      (j <     NQ4)           { src = q;  dst = qf; }
    else if (j < 2 * NQ4)           { src = k;  dst = kf;  j -= NQ4; }
    else if (j < 3 * NQ4)           { src = v;  dst = vf;  j -= 2 * NQ4; }
    else if (j < 3 * NQ4 + NW4)     { src = Wq; dst = Wqf; j -= 3 * NQ4; }
    else if (j < 3 * NQ4 + 2 * NW4) { src = Wk; dst = Wkf; j -= 3 * NQ4 + NW4; }
    else                            { src = Wv; dst = Wvf; j -= 3 * NQ4 + 2 * NW4; }
    float4 vv = ((const float4*)src)[j];
    f16x4 o;
    o[0] = (f16)vv.x; o[1] = (f16)vv.y; o[2] = (f16)vv.z; o[3] = (f16)vv.w;
    ((f16x4*)dst)[j] = o;
  }
}

__global__ void reduce_l(const float* __restrict__ lpart, float* __restrict__ lsum, int n) {
  int i = blockIdx.x * blockDim.x + threadIdx.x;
  if (i < n) {
    float s = 0.f;
    #pragma unroll
    for (int j = 0; j < 32; ++j) s += lpart[(long)i * 32 + j];
    lsum[i] = s;
  }
}

extern "C" void kernel_launch(void* const* d_in, const int* in_sizes, int n_in,
                              void* d_out, int out_size, void* d_ws, size_t ws_size,
                              hipStream_t stream)
{
  const float* q    = (const float*)d_in[0];
  const float* k    = (const float*)d_in[1];
  const float* v    = (const float*)d_in[2];
  const float* mask = (const float*)d_in[3];
  const float* Wq   = (const float*)d_in[4];
  const float* Wk   = (const float*)d_in[5];
  const float* Wv   = (const float*)d_in[6];
  float* out = (float*)d_out;
  char*  ws  = (char*)d_ws;

  // workspace layout (bytes); q/k/v fp16 region is dead after projections -> reused for P
  f16* qf  = (f16*)(ws + 0);            // 32 MB
  f16* kf  = (f16*)(ws + 33554432);     // 32 MB
  f16* vf  = (f16*)(ws + 67108864);     // 32 MB
  f16* Pm  = (f16*)(ws + 0);            // 64 MB (reuse of qf/kf/vf region)
  f16* Wqf = (f16*)(ws + 100663296);    // 2 MB
  f16* Wkf = (f16*)(ws + 102760448);
  f16* Wvf = (f16*)(ws + 104857600);
  f16* qp  = (f16*)(ws + 106954752);    // 32 MB
  f16* kp  = (f16*)(ws + 140509184);    // 32 MB
  f16* vpT = (f16*)(ws + 174063616);    // 32 MB  (stored H x J, i.e. transposed)
  float* lpart = (float*)(ws + 207618048); // 2 MB
  float* lsum  = (float*)(ws + 209715200); // 64 KB

  const long L = 2048, J = 2048, D = 1024, H = 1024;

  // 1) fp32 -> fp16 converts (single launch)
  cvt_all<<<dim3(2048), dim3(256), 0, stream>>>(q, k, v, Wq, Wk, Wv, qf, kf, vf, Wqf, Wkf, Wvf);

  // 2) projections
  // qp[bl,h] = sum_d q[bl,d] * Wq[h,d]     M=16384 N=1024 K=1024
  gemm_bt<0><<<dim3(1024 / BN, 16384 / BM, 1), dim3(512), 0, stream>>>(
      qf, Wqf, qp, 16384, 1024, 1024, 1024, 1024, 1024,
      0, 0, 0, nullptr, 0, nullptr, 0.f);
  // kp[bj,h] = sum_d k[bj,d] * Wk[h,d]
  gemm_bt<0><<<dim3(1024 / BN, 16384 / BM, 1), dim3(512), 0, stream>>>(
      kf, Wkf, kp, 16384, 1024, 1024, 1024, 1024, 1024,
      0, 0, 0, nullptr, 0, nullptr, 0.f);
  // vpT[b][h,j] = sum_d Wv[h,d] * v[b][j,d]   M=1024 N=2048 K=1024, batched over b
  gemm_bt<0><<<dim3(2048 / BN, 1024 / BM, 8), dim3(512), 0, stream>>>(
      Wvf, vf, vpT, 1024, 2048, 1024, 1024, 1024, 2048,
      0, J * D, H * J, nullptr, 0, nullptr, 0.f);

  // 3) P[b][l,j] = exp(qp.kp^T / 32 + mask), fp16, + row-sum partials
  gemm_bt<1><<<dim3(2048 / BN, 2048 / BM, 8), dim3(512), 0, stream>>>(
      qp, kp, Pm, 2048, 2048, 1024, 1024, 1024, 2048,
      L * H, J * H, L * J, mask, L * J, lpart, 0.03125f);

  reduce_l<<<dim3(16384 / 256), dim3(256), 0, stream>>>(lpart, lsum, 16384);

  // 4) out[b][l,h] = (sum_j P[l,j] * vpT[h,j]) / l[b,l]   M=2048 N=1024 K=2048
  gemm_bt<2><<<dim3(1024 / BN, 2048 / BM, 8), dim3(512), 0, stream>>>(
      Pm, vpT, out, 2048, 1024, 2048, 2048, 2048, 1024,
      L * J, H * J, L * H, nullptr, 0, lsum, 0.f);
}